// Round 12
// baseline (630.090 us; speedup 1.0000x reference)
//
#include <hip/hip_runtime.h>

// ---------------- common helpers ----------------
typedef unsigned short ushortT;
typedef unsigned int uint32;
typedef __attribute__((ext_vector_type(8))) short short8;
typedef __attribute__((ext_vector_type(4))) float f32x4;

__device__ __forceinline__ ushortT f2bf(float f) {
    uint32 u = __float_as_uint(f);
    uint32 r = (u + 0x7fffu + ((u >> 16) & 1u)) >> 16;
    return (ushortT)r;
}
__device__ __forceinline__ float bf2f(uint32 v) {
    return __uint_as_float(v << 16);
}

__device__ __forceinline__ void unpack8(uint4 v, float* f) {
    f[0] = bf2f(v.x & 0xffffu); f[1] = bf2f(v.x >> 16);
    f[2] = bf2f(v.y & 0xffffu); f[3] = bf2f(v.y >> 16);
    f[4] = bf2f(v.z & 0xffffu); f[5] = bf2f(v.z >> 16);
    f[6] = bf2f(v.w & 0xffffu); f[7] = bf2f(v.w >> 16);
}

// async global->LDS, 16B per lane. LDS dest must be wave-uniform base;
// HW writes lane i at base + i*16.
typedef __attribute__((address_space(1))) const void gvoid;
typedef __attribute__((address_space(3))) void lvoid;
__device__ __forceinline__ void gld16(const ushortT* g, ushortT* l) {
    __builtin_amdgcn_global_load_lds((gvoid*)g, (lvoid*)l, 16, 0, 0);
}

// ---------------- fp32 -> bf16 convert: x (activation) ----------------
__global__ __launch_bounds__(256) void f32_to_bf16_kernel(
    const float* __restrict__ src, ushortT* __restrict__ dst, int n4)
{
    int i = blockIdx.x * 256 + threadIdx.x;
    if (i < n4) {
        float4 v = reinterpret_cast<const float4*>(src)[i];
        ushort4 o;
        o.x = f2bf(v.x); o.y = f2bf(v.y); o.z = f2bf(v.z); o.w = f2bf(v.w);
        reinterpret_cast<ushort4*>(dst)[i] = o;
    }
}

// ---------------- all 4 weight matrices -> one contiguous bf16 buffer ----
__global__ __launch_bounds__(256) void wconv_kernel(
    const float* __restrict__ s0, const float* __restrict__ s1,
    const float* __restrict__ s2, const float* __restrict__ s3,
    ushortT* __restrict__ dst)
{
    int i = blockIdx.x * 256 + threadIdx.x;      // 0 .. 4*262144-1
    const int wsel = i >> 18;
    const int off  = i & 262143;
    const float* s = (wsel == 0) ? s0 : (wsel == 1 ? s1 : (wsel == 2 ? s2 : s3));
    float4 v = reinterpret_cast<const float4*>(s)[off];
    ushort4 o;
    o.x = f2bf(v.x); o.y = f2bf(v.y); o.z = f2bf(v.z); o.w = f2bf(v.w);
    reinterpret_cast<ushort4*>(dst)[i] = o;
}

// ---------------- pack q/k/v biases into one 3072-float buffer ----------------
__global__ __launch_bounds__(256) void pack_bias_kernel(
    const float* __restrict__ bq, const float* __restrict__ bk,
    const float* __restrict__ bv, float* __restrict__ out)
{
    int i = blockIdx.x * 256 + threadIdx.x;   // 3072
    float v = (i < 1024) ? bq[i] : (i < 2048 ? bk[i - 1024] : bv[i - 2048]);
    out[i] = v;
}

// ---------------- RoPE cos/sin table: [T][16] float2 ----------------
__global__ __launch_bounds__(256) void rope_table_kernel(float2* __restrict__ tab)
{
    int idx = blockIdx.x * 256 + threadIdx.x;   // T*16 = 131072 entries
    int t = idx >> 4;
    int i = idx & 15;
    float inv = powf(10000.0f, -(float)i / 16.0f);
    float ang = (float)t * inv;
    tab[idx] = make_float2(cosf(ang), sinf(ang));
}

// swizzled LDS fragment read: region has 32-col rows; e ^= ((row>>1)&3)<<3
__device__ __forceinline__ short8 ldsfrag(const ushortT* region, int row, int g) {
    int e = (row << 5) + (g << 3);
    e ^= ((row >> 1) & 3) << 3;
    return *reinterpret_cast<const short8*>(region + e);
}

#define MC_ ((size_t)33554432)   // 32768 * 1024

// ---------------- 256x128-tile bf16 MFMA GEMM ----------------
// K-loop: r10 structure EXACTLY (rolled, unroll 1) -- r11's full unroll
// regressed 364->415 us (icache), VALU removal did NOT raise MfmaUtil ->
// issue-port theory falsified.
// r11 post-mortem: out-proj (same K-loop, trivial epilogue) runs ~1.4x qkv
// per FLOP -> the MODE3 EPILOGUE is the cost: 16 __shfl (DS pipe) + 32
// scattered stores/thread; 32B bf16 chunks amplify ~192MB of HBM writes
// (ideal 448, measured 662). Fix: LDS-coalesced epilogue -- round-trip acc
// through LDS (fp32 [64][132], reuses staging LDS post-loop); each thread
// then owns 16 consecutive cols of one row: rope pairs in-lane (no shfl),
// bf16 stores 64-256B contiguous, present stores full 256B d-rows.
//
// Tile: 256x128, 512 thr = 8 waves (4m x 2n), wave 64x64 = 4x4 frags,
// BK=32, LDS 2 x 24KB = 48KB. syncthreads-per-tile schedule.
// XCD co-location: per proj-phase 1024 blocks = 8 xcd x (16 tm x 8 tn).
// W per phase = 2MB (L2 budget, r4/r9 lesson).
//
// MODE 3: merged qkv dispatch, grid 3072; proj = bid>>10 in {0,1,2}.
//   proj 0 (q): rope -> bf16; proj 1/2 (k/v): fp32 present (pre-rope,
//   (B,H,T,64)) + rope -> bf16.
// MODE 2: fp32 out, no rope (final projection), grid 1024, direct stores.
template<int MODE>
__global__ __launch_bounds__(512, 4) void gemm_wide_kernel(
    const ushortT* __restrict__ A,    // M x K bf16
    const ushortT* __restrict__ Wall, // MODE3: [wq;wk;wv] (3*1024 x K); MODE2: 1024 x K
    const float*   __restrict__ biasAll, // MODE3: 3072; MODE2: 1024
    const float2*  __restrict__ tab,  // rope table [T][16]
    ushortT*       __restrict__ CbAll,// MODE3: qlin (klin=+MC, vlin=+2MC)
    float*         __restrict__ CfAll,// MODE3: presK (presV=+MC); MODE2: MxN fp32
    int M, int N, int K)
{
    __shared__ ushortT lds[2 * 12288];  // 2 bufs x (A 8192 + B 4096) elems = 48 KB
    const int tid  = threadIdx.x;
    const int lane = tid & 63;
    const int wv   = tid >> 6;        // 0..7
    const int wm   = wv >> 1;         // 0..3  (64-row quarter of 256)
    const int wn   = wv & 1;          // 0..1  (64-col half of 128)
    const int g    = lane >> 4;       // k sub-block 0..3 (also C/D row group)
    const int rsel = lane & 15;

    // projection select (MODE 3) + per-projection block id
    const int bidAll = blockIdx.x;
    const int proj   = (MODE == 3) ? (bidAll >> 10) : 0;
    const int bid    = (MODE == 3) ? (bidAll & 1023) : bidAll;

    const ushortT* W    = Wall + (size_t)proj * 1024 * K;
    const float*   bias = biasAll + proj * 1024;

    // XCD co-location: 1024 blocks = 8 xcd x (16 tm x 8 tn)
    const int xi  = bid & 7;
    const int j   = bid >> 3;
    const int tn  = j & 7;
    const int tm  = xi * 16 + (j >> 3);
    const int m0  = tm * 256, n0 = tn * 128;

    // staging source: chunk c -> row c>>2, col8 = (c&3)^((c>>3)&3)
    // (pre-swizzled global source; LDS dest stays linear: chunk*16B)
    const int crow = tid >> 2;                       // 0..127
    const int ccol = ((tid & 3) ^ ((tid >> 3) & 3)) * 8;
    const ushortT* gA0 = A + (size_t)(m0 + crow) * K + ccol;   // A rows 0..127
    const ushortT* gA1 = gA0 + (size_t)128 * K;                // A rows 128..255
    const ushortT* gB0 = W + (size_t)(n0 + crow) * K + ccol;   // B rows 0..127

    // wave-uniform LDS dest bases (element offsets within a 12288-elem buffer)
    const int dA0 = wv * 512;           // A chunks tid       (rows 0..127)
    const int dA1 = 4096 + wv * 512;    // A chunks tid+512   (rows 128..255)
    const int dB  = 8192 + wv * 512;    // B chunks tid       (rows 0..127)

    #define STAGE(buf, t) { \
        ushortT* b_ = lds + (buf) * 12288; \
        gld16(gA0 + (t) * 32, b_ + dA0); \
        gld16(gA1 + (t) * 32, b_ + dA1); \
        gld16(gB0 + (t) * 32, b_ + dB); \
    }

    f32x4 acc[4][4] = {};
    const int NT = K >> 5;   // 32 K-tiles
    int cur = 0;

    STAGE(0, 0);

    #pragma unroll 1
    for (int t = 0; t < NT; ++t) {
        __syncthreads();   // drains vmcnt+lgkm: buf[cur] staged, prior reads done
        if (t + 1 < NT) STAGE(cur ^ 1, t + 1);

        const ushortT* ra = lds + cur * 12288;
        const ushortT* rb = ra + 8192;
        short8 Af[4], Bf[4];
        #pragma unroll
        for (int fm = 0; fm < 4; ++fm) Af[fm] = ldsfrag(ra, wm * 64 + fm * 16 + rsel, g);
        #pragma unroll
        for (int fn = 0; fn < 4; ++fn) Bf[fn] = ldsfrag(rb, wn * 64 + fn * 16 + rsel, g);
        #pragma unroll
        for (int fm = 0; fm < 4; ++fm)
            #pragma unroll
            for (int fn = 0; fn < 4; ++fn)
                acc[fm][fn] = __builtin_amdgcn_mfma_f32_16x16x32_bf16(Af[fm], Bf[fn], acc[fm][fn], 0, 0, 0);
        cur ^= 1;
    }
    #undef STAGE

    if (MODE == 3) {
        // ---- LDS-coalesced epilogue: 4 fm-chunks of 64 rows x 128 cols ----
        // write: LDS[ri][col] fp32, [64][132] padded (33792B <= 48KB free).
        // readback: thread owns 16 consecutive cols of one row.
        float* ldsf = (float*)lds;
        const int ri   = wm * 16 + g * 4;     // + e -> LDS row of acc value
        const int colw = wn * 64;             // + fn*16 + rsel -> LDS col
        const int rrow = tid >> 3;            // readback LDS row 0..63
        const int rcol = (tid & 7) * 16;      // readback col base (mult of 16)
        const int col0 = n0 + rcol;           // global col base
        const int h    = col0 >> 6;           // head (0..15 within proj)
        const int d0   = col0 & 63;           // dim base within head

        #pragma unroll
        for (int fm = 0; fm < 4; ++fm) {
            __syncthreads();                  // LDS free (K-loop or prev chunk done)
            #pragma unroll
            for (int fn = 0; fn < 4; ++fn) {
                const float bv = bias[n0 + colw + fn * 16 + rsel];
                #pragma unroll
                for (int e = 0; e < 4; ++e)
                    ldsf[(ri + e) * 132 + colw + fn * 16 + rsel] = acc[fm][fn][e] + bv;
            }
            __syncthreads();
            const int row = m0 + (rrow >> 4) * 64 + fm * 16 + (rrow & 15);
            const int t   = row & 8191;
            const int b   = row >> 13;
            float* pf = CfAll + (size_t)(proj - 1) * MC_ +
                        (((size_t)b * 16 + h) * 8192 + t) * 64 + d0;
            ushortT* qb = CbAll + (size_t)proj * MC_ + (size_t)row * 1024 + col0;
            const float2* tb = tab + t * 16 + (d0 >> 1);
            #pragma unroll
            for (int rr = 0; rr < 4; ++rr) {
                f32x4 v4 = *reinterpret_cast<const f32x4*>(
                    &ldsf[rrow * 132 + rcol + rr * 4]);
                if (proj != 0)               // present: pre-rope, 256B d-rows
                    *reinterpret_cast<f32x4*>(pf + rr * 4) = v4;
                if (d0 < 32) {               // rope: pairs in-lane, no shfl
                    const float2 c0 = tb[rr * 2];
                    const float2 c1 = tb[rr * 2 + 1];
                    const float a0 = v4[0] * c0.x - v4[1] * c0.y;
                    const float a1 = v4[1] * c0.x + v4[0] * c0.y;
                    const float a2 = v4[2] * c1.x - v4[3] * c1.y;
                    const float a3 = v4[3] * c1.x + v4[2] * c1.y;
                    v4[0] = a0; v4[1] = a1; v4[2] = a2; v4[3] = a3;
                }
                ushort4 s;
                s.x = f2bf(v4[0]); s.y = f2bf(v4[1]);
                s.z = f2bf(v4[2]); s.w = f2bf(v4[3]);
                *reinterpret_cast<ushort4*>(qb + rr * 4) = s;
            }
        }
    } else {
        // MODE 2: direct fp32 stores (already 64B-coalesced)
        #pragma unroll
        for (int fn = 0; fn < 4; ++fn) {
            const int colb = n0 + wn * 64 + fn * 16 + rsel;
            const float bv = bias[colb];
            #pragma unroll
            for (int fm = 0; fm < 4; ++fm) {
                const int rowbase = m0 + wm * 64 + fm * 16 + g * 4;
                #pragma unroll
                for (int e = 0; e < 4; ++e) {
                    const int row = rowbase + e;
                    CfAll[(size_t)row * N + colb] = acc[fm][fn][e] + bv;
                }
            }
        }
    }
}

// ---------------- neighborhood attention ----------------
// wave = 8 queries x 8 dim-chunks; lane = tloc*8 + c  (8 consecutive lanes
// cover one contiguous 128B row segment). q/k/v already roped.
__global__ __launch_bounds__(256) void natt_kernel(
    const ushortT* __restrict__ Q,
    const ushortT* __restrict__ Kl,
    const ushortT* __restrict__ Vl,
    ushortT*       __restrict__ O)
{
    const int T = 8192;
    const int tid  = threadIdx.x;
    const int lane = tid & 63;
    const int tloc = lane >> 3;
    const int c    = lane & 7;

    const int wq   = (blockIdx.x * 256 + tid) >> 6;  // wave-group id
    const int qidx = wq * 8 + tloc;
    const int t = qidx & (T - 1);
    const int h = (qidx >> 13) & 15;
    const int b = qidx >> 17;

    const int shifts[4] = {0, 2, 3, 4};
    const int sh = shifts[h >> 2];
    const int dd = 1 << sh;

    const int r  = t & (dd - 1);
    const int p  = t >> sh;
    const int Lr = ((T - 1 - r) >> sh) + 1;
    int s = p - 3;
    const int smax = Lr - 7;
    s = s < 0 ? 0 : (s > smax ? smax : s);
    const int tbase = r + (s << sh);

    const size_t qoff = ((size_t)(b * T + t)) * 1024 + h * 64 + c * 8;
    float qf[8];
    unpack8(*reinterpret_cast<const uint4*>(Q + qoff), qf);

    const size_t cbase = ((size_t)b * T) * 1024 + h * 64 + c * 8;

    float sc[7];
    #pragma unroll
    for (int j = 0; j < 7; ++j) {
        const int tj = tbase + (j << sh);
        float kf[8];
        unpack8(*reinterpret_cast<const uint4*>(Kl + cbase + (size_t)tj * 1024), kf);
        float pp = 0.f;
        #pragma unroll
        for (int i = 0; i < 8; ++i) pp = fmaf(qf[i], kf[i], pp);
        pp += __shfl_xor(pp, 1, 64);
        pp += __shfl_xor(pp, 2, 64);
        pp += __shfl_xor(pp, 4, 64);
        sc[j] = pp;
    }

    float mx = sc[0];
    #pragma unroll
    for (int j = 1; j < 7; ++j) mx = fmaxf(mx, sc[j]);
    float den = 0.f;
    #pragma unroll
    for (int j = 0; j < 7; ++j) { sc[j] = __expf(sc[j] - mx); den += sc[j]; }
    const float inv = 1.0f / den;

    float out[8] = {};
    #pragma unroll
    for (int j = 0; j < 7; ++j) {
        const int tj = tbase + (j << sh);
        float vf[8];
        unpack8(*reinterpret_cast<const uint4*>(Vl + cbase + (size_t)tj * 1024), vf);
        #pragma unroll
        for (int i = 0; i < 8; ++i) out[i] = fmaf(sc[j], vf[i], out[i]);
    }

    short8 ov;
    #pragma unroll
    for (int i = 0; i < 8; ++i) ov[i] = (short)f2bf(out[i] * inv);
    *reinterpret_cast<short8*>(const_cast<ushortT*>(O + qoff)) = ov;
}

// ---------------- launcher ----------------
extern "C" void kernel_launch(void* const* d_in, const int* in_sizes, int n_in,
                              void* d_out, int out_size, void* d_ws, size_t ws_size,
                              hipStream_t stream)
{
    const float* x  = (const float*)d_in[0];
    const float* wq = (const float*)d_in[1];
    const float* bq = (const float*)d_in[2];
    const float* wk = (const float*)d_in[3];
    const float* bk = (const float*)d_in[4];
    const float* wv = (const float*)d_in[5];
    const float* bv = (const float*)d_in[6];
    const float* wp = (const float*)d_in[7];
    const float* bp = (const float*)d_in[8];

    const int B = 4, T = 8192, C = 1024;
    const int M = B * T;                    // 32768
    const size_t MC = (size_t)M * C;        // 33,554,432

    char* ws = (char*)d_ws;
    ushortT* xb    = (ushortT*)ws;                                  // 64MB (reused as attn out)
    ushortT* wallb = (ushortT*)(ws + (size_t)64 * 1024 * 1024);     // 8MB: [wq][wk][wv][wp]
    ushortT* wpb   = wallb + (size_t)3 * C * C;
    ushortT* qlin  = (ushortT*)(ws + (size_t)72 * 1024 * 1024);     // 64MB (klin,vlin follow)
    ushortT* klin  = qlin + MC;
    ushortT* vlin  = klin + MC;
    float2*  tab   = (float2*)(ws + (size_t)264 * 1024 * 1024);     // 1MB
    float*   bqkv  = (float*)(ws + (size_t)266 * 1024 * 1024);      // 12KB

    float* y     = (float*)d_out;
    float* presK = y + MC;                  // presV = presK + MC (contiguous)

    rope_table_kernel<<<512, 256, 0, stream>>>(tab);
    pack_bias_kernel<<<12, 256, 0, stream>>>(bq, bk, bv, bqkv);

    f32_to_bf16_kernel<<<(int)(MC / 4 / 256), 256, 0, stream>>>(x, xb, (int)(MC / 4));
    wconv_kernel<<<4 * (C * C / 4) / 256, 256, 0, stream>>>(wq, wk, wv, wp, wallb);

    // merged qkv dispatch: grid 3072 = 3 proj x 1024 blocks (256x128 tiles)
    gemm_wide_kernel<3><<<3072, 512, 0, stream>>>(
        xb, wallb, bqkv, tab, qlin, presK, M, C, C);

    natt_kernel<<<(B * 16 * T) / 32, 256, 0, stream>>>(qlin, klin, vlin, xb);

    // output projection: grid 1024
    gemm_wide_kernel<2><<<1024, 512, 0, stream>>>(
        xb, wpb, bp, tab, nullptr, y, M, C, C);
}

// Round 14
// 569.137 us; speedup vs baseline: 1.1071x; 1.1071x over previous
//
#include <hip/hip_runtime.h>

// ---------------- common helpers ----------------
typedef unsigned short ushortT;
typedef unsigned int uint32;
typedef __attribute__((ext_vector_type(8))) short short8;
typedef __attribute__((ext_vector_type(4))) float f32x4;

__device__ __forceinline__ ushortT f2bf(float f) {
    uint32 u = __float_as_uint(f);
    uint32 r = (u + 0x7fffu + ((u >> 16) & 1u)) >> 16;
    return (ushortT)r;
}
__device__ __forceinline__ float bf2f(uint32 v) {
    return __uint_as_float(v << 16);
}

__device__ __forceinline__ void unpack8(uint4 v, float* f) {
    f[0] = bf2f(v.x & 0xffffu); f[1] = bf2f(v.x >> 16);
    f[2] = bf2f(v.y & 0xffffu); f[3] = bf2f(v.y >> 16);
    f[4] = bf2f(v.z & 0xffffu); f[5] = bf2f(v.z >> 16);
    f[6] = bf2f(v.w & 0xffffu); f[7] = bf2f(v.w >> 16);
}

// async global->LDS, 16B per lane. LDS dest must be wave-uniform base;
// HW writes lane i at base + i*16.
typedef __attribute__((address_space(1))) const void gvoid;
typedef __attribute__((address_space(3))) void lvoid;
__device__ __forceinline__ void gld16(const ushortT* g, ushortT* l) {
    __builtin_amdgcn_global_load_lds((gvoid*)g, (lvoid*)l, 16, 0, 0);
}

// ---------------- fp32 -> bf16 convert: x (activation) ----------------
__global__ __launch_bounds__(256) void f32_to_bf16_kernel(
    const float* __restrict__ src, ushortT* __restrict__ dst, int n4)
{
    int i = blockIdx.x * 256 + threadIdx.x;
    if (i < n4) {
        float4 v = reinterpret_cast<const float4*>(src)[i];
        ushort4 o;
        o.x = f2bf(v.x); o.y = f2bf(v.y); o.z = f2bf(v.z); o.w = f2bf(v.w);
        reinterpret_cast<ushort4*>(dst)[i] = o;
    }
}

// ---------------- all 4 weight matrices -> one contiguous bf16 buffer ----
__global__ __launch_bounds__(256) void wconv_kernel(
    const float* __restrict__ s0, const float* __restrict__ s1,
    const float* __restrict__ s2, const float* __restrict__ s3,
    ushortT* __restrict__ dst)
{
    int i = blockIdx.x * 256 + threadIdx.x;      // 0 .. 4*262144-1
    const int wsel = i >> 18;
    const int off  = i & 262143;
    const float* s = (wsel == 0) ? s0 : (wsel == 1 ? s1 : (wsel == 2 ? s2 : s3));
    float4 v = reinterpret_cast<const float4*>(s)[off];
    ushort4 o;
    o.x = f2bf(v.x); o.y = f2bf(v.y); o.z = f2bf(v.z); o.w = f2bf(v.w);
    reinterpret_cast<ushort4*>(dst)[i] = o;
}

// ---------------- pack q/k/v biases into one 3072-float buffer ----------------
__global__ __launch_bounds__(256) void pack_bias_kernel(
    const float* __restrict__ bq, const float* __restrict__ bk,
    const float* __restrict__ bv, float* __restrict__ out)
{
    int i = blockIdx.x * 256 + threadIdx.x;   // 3072
    float v = (i < 1024) ? bq[i] : (i < 2048 ? bk[i - 1024] : bv[i - 2048]);
    out[i] = v;
}

// ---------------- RoPE cos/sin table: [T][16] float2 ----------------
__global__ __launch_bounds__(256) void rope_table_kernel(float2* __restrict__ tab)
{
    int idx = blockIdx.x * 256 + threadIdx.x;   // T*16 = 131072 entries
    int t = idx >> 4;
    int i = idx & 15;
    float inv = powf(10000.0f, -(float)i / 16.0f);
    float ang = (float)t * inv;
    tab[idx] = make_float2(cosf(ang), sinf(ang));
}

// swizzled LDS fragment read: region has 32-col rows; e ^= ((row>>1)&3)<<3
__device__ __forceinline__ short8 ldsfrag(const ushortT* region, int row, int g) {
    int e = (row << 5) + (g << 3);
    e ^= ((row >> 1) & 3) << 3;
    return *reinterpret_cast<const short8*>(region + e);
}

#define MC_ ((size_t)33554432)   // 32768 * 1024

// ---------------- 256x128-tile bf16 MFMA GEMM (round-10 config, 573us) ----
// r13 post-mortem: persistent-blocks + NT-stores bundle FAILED correctness
// (absmax 1.75, root cause not identified) -> full revert to this proven
// config. GEMM campaign summary: five structures all land ~500-570 TF with
// every pipe <=25%; no validated theory remains for the gap -> GEMM frozen.
//
// Tile: 256x128, 512 thr = 8 waves (4m x 2n), wave 64x64 = 4x4 frags,
// BK=32, LDS 2 x 24KB = 48KB, rolled K-loop (r11 unroll regressed: icache),
// syncthreads-per-tile schedule (r7/r8: sync style not the lever).
// XCD co-location: per proj-phase 1024 blocks = 8 xcd x (16 tm x 8 tn).
// W per phase = 2MB (L2 budget, r4/r9 lesson).
//
// MODE 3: merged qkv dispatch, grid 3072; proj = bid>>10 in {0,1,2}.
//   proj 0 (q): rope -> bf16; proj 1/2 (k/v): fp32 present (pre-rope,
//   (B,H,T,64)) + rope -> bf16.
// MODE 2: fp32 out, no rope (final projection), grid 1024, direct stores.
template<int MODE>
__global__ __launch_bounds__(512, 4) void gemm_wide_kernel(
    const ushortT* __restrict__ A,    // M x K bf16
    const ushortT* __restrict__ Wall, // MODE3: [wq;wk;wv] (3*1024 x K); MODE2: 1024 x K
    const float*   __restrict__ biasAll, // MODE3: 3072; MODE2: 1024
    const float2*  __restrict__ tab,  // rope table [T][16]
    ushortT*       __restrict__ CbAll,// MODE3: qlin (klin=+MC, vlin=+2MC)
    float*         __restrict__ CfAll,// MODE3: presK (presV=+MC); MODE2: MxN fp32
    int M, int N, int K)
{
    __shared__ ushortT lds[2 * 12288];  // 2 bufs x (A 8192 + B 4096) elems = 48 KB
    const int tid  = threadIdx.x;
    const int lane = tid & 63;
    const int wv   = tid >> 6;        // 0..7
    const int wm   = wv >> 1;         // 0..3  (64-row quarter of 256)
    const int wn   = wv & 1;          // 0..1  (64-col half of 128)
    const int g    = lane >> 4;       // k sub-block 0..3 (also C/D row group)
    const int rsel = lane & 15;

    // projection select (MODE 3) + per-projection block id
    const int bidAll = blockIdx.x;
    const int proj   = (MODE == 3) ? (bidAll >> 10) : 0;
    const int bid    = (MODE == 3) ? (bidAll & 1023) : bidAll;

    const ushortT* W    = Wall + (size_t)proj * 1024 * K;
    const float*   bias = biasAll + proj * 1024;

    // XCD co-location: 1024 blocks = 8 xcd x (16 tm x 8 tn)
    const int xi  = bid & 7;
    const int j   = bid >> 3;
    const int tn  = j & 7;
    const int tm  = xi * 16 + (j >> 3);
    const int m0  = tm * 256, n0 = tn * 128;

    // staging source: chunk c -> row c>>2, col8 = (c&3)^((c>>3)&3)
    // (pre-swizzled global source; LDS dest stays linear: chunk*16B)
    const int crow = tid >> 2;                       // 0..127
    const int ccol = ((tid & 3) ^ ((tid >> 3) & 3)) * 8;
    const ushortT* gA0 = A + (size_t)(m0 + crow) * K + ccol;   // A rows 0..127
    const ushortT* gA1 = gA0 + (size_t)128 * K;                // A rows 128..255
    const ushortT* gB0 = W + (size_t)(n0 + crow) * K + ccol;   // B rows 0..127

    // wave-uniform LDS dest bases (element offsets within a 12288-elem buffer)
    const int dA0 = wv * 512;           // A chunks tid       (rows 0..127)
    const int dA1 = 4096 + wv * 512;    // A chunks tid+512   (rows 128..255)
    const int dB  = 8192 + wv * 512;    // B chunks tid       (rows 0..127)

    #define STAGE(buf, t) { \
        ushortT* b_ = lds + (buf) * 12288; \
        gld16(gA0 + (t) * 32, b_ + dA0); \
        gld16(gA1 + (t) * 32, b_ + dA1); \
        gld16(gB0 + (t) * 32, b_ + dB); \
    }

    f32x4 acc[4][4] = {};
    const int NT = K >> 5;   // 32 K-tiles
    int cur = 0;

    STAGE(0, 0);

    #pragma unroll 1
    for (int t = 0; t < NT; ++t) {
        __syncthreads();   // drains vmcnt+lgkm: buf[cur] staged, prior reads done
        if (t + 1 < NT) STAGE(cur ^ 1, t + 1);

        const ushortT* ra = lds + cur * 12288;
        const ushortT* rb = ra + 8192;
        short8 Af[4], Bf[4];
        #pragma unroll
        for (int fm = 0; fm < 4; ++fm) Af[fm] = ldsfrag(ra, wm * 64 + fm * 16 + rsel, g);
        #pragma unroll
        for (int fn = 0; fn < 4; ++fn) Bf[fn] = ldsfrag(rb, wn * 64 + fn * 16 + rsel, g);
        #pragma unroll
        for (int fm = 0; fm < 4; ++fm)
            #pragma unroll
            for (int fn = 0; fn < 4; ++fn)
                acc[fm][fn] = __builtin_amdgcn_mfma_f32_16x16x32_bf16(Af[fm], Bf[fn], acc[fm][fn], 0, 0, 0);
        cur ^= 1;
    }
    #undef STAGE

    // epilogue: C/D layout col = rsel, row = g*4 + e (within 16x16 frag)
    #pragma unroll
    for (int fn = 0; fn < 4; ++fn) {
        const int colb = n0 + wn * 64 + fn * 16 + rsel;   // 0..1023
        const int d    = colb & 63;
        const float bv = bias[colb];
        #pragma unroll
        for (int fm = 0; fm < 4; ++fm) {
            const int rowbase = m0 + wm * 64 + fm * 16 + g * 4;
            #pragma unroll
            for (int e = 0; e < 4; ++e) {
                const int row = rowbase + e;
                const float val = acc[fm][fn][e] + bv;
                if (MODE == 2) {
                    CfAll[(size_t)row * N + colb] = val;
                } else {
                    if (proj != 0) {
                        // present: (B, H, T, 64) fp32, pre-rope
                        const int b = row >> 13, t = row & 8191;
                        const int h = colb >> 6;
                        CfAll[(size_t)(proj - 1) * MC_ +
                              (((size_t)b * 16 + h) * 8192 + t) * 64 + d] = val;
                    }
                    // rope: pair (d, d^1) sits at lane^1, same row
                    const float pv = __shfl_xor(val, 1, 64);
                    float ov = val;
                    if (d < 32) {
                        const int t = row & 8191;
                        const float2 cs = tab[t * 16 + (d >> 1)];
                        ov = (d & 1) ? fmaf(val, cs.x,  pv * cs.y)
                                     : fmaf(val, cs.x, -pv * cs.y);
                    }
                    CbAll[(size_t)proj * MC_ + (size_t)row * 1024 + colb] = f2bf(ov);
                }
            }
        }
    }
}

// ---------------- neighborhood attention ----------------
// wave = 8 queries x 8 dim-chunks; lane = tloc*8 + c  (8 consecutive lanes
// cover one contiguous 128B row segment). q/k/v already roped.
// r13: XCD-chunk swizzle (bijective: 16384 = 8 x 2048). Consecutive
// logical blocks = consecutive t within one (b,h); their 7-wide K/V
// windows overlap ~6/7 -> keeping a contiguous t-range per XCD makes the
// streaming window L2-resident instead of duplicated across 8 XCDs.
__global__ __launch_bounds__(256) void natt_kernel(
    const ushortT* __restrict__ Q,
    const ushortT* __restrict__ Kl,
    const ushortT* __restrict__ Vl,
    ushortT*       __restrict__ O)
{
    const int T = 8192;
    const int tid  = threadIdx.x;
    const int lane = tid & 63;
    const int tloc = lane >> 3;
    const int c    = lane & 7;

    // XCD-chunk swizzle: grid 16384 = 8 xcd x 2048 logical blocks
    const int sbid = (blockIdx.x & 7) * 2048 + (blockIdx.x >> 3);
    const int wq   = sbid * 4 + (tid >> 6);          // wave-group id
    const int qidx = wq * 8 + tloc;
    const int t = qidx & (T - 1);
    const int h = (qidx >> 13) & 15;
    const int b = qidx >> 17;

    const int shifts[4] = {0, 2, 3, 4};
    const int sh = shifts[h >> 2];
    const int dd = 1 << sh;

    const int r  = t & (dd - 1);
    const int p  = t >> sh;
    const int Lr = ((T - 1 - r) >> sh) + 1;
    int s = p - 3;
    const int smax = Lr - 7;
    s = s < 0 ? 0 : (s > smax ? smax : s);
    const int tbase = r + (s << sh);

    const size_t qoff = ((size_t)(b * T + t)) * 1024 + h * 64 + c * 8;
    float qf[8];
    unpack8(*reinterpret_cast<const uint4*>(Q + qoff), qf);

    const size_t cbase = ((size_t)b * T) * 1024 + h * 64 + c * 8;

    float sc[7];
    #pragma unroll
    for (int j = 0; j < 7; ++j) {
        const int tj = tbase + (j << sh);
        float kf[8];
        unpack8(*reinterpret_cast<const uint4*>(Kl + cbase + (size_t)tj * 1024), kf);
        float pp = 0.f;
        #pragma unroll
        for (int i = 0; i < 8; ++i) pp = fmaf(qf[i], kf[i], pp);
        pp += __shfl_xor(pp, 1, 64);
        pp += __shfl_xor(pp, 2, 64);
        pp += __shfl_xor(pp, 4, 64);
        sc[j] = pp;
    }

    float mx = sc[0];
    #pragma unroll
    for (int j = 1; j < 7; ++j) mx = fmaxf(mx, sc[j]);
    float den = 0.f;
    #pragma unroll
    for (int j = 0; j < 7; ++j) { sc[j] = __expf(sc[j] - mx); den += sc[j]; }
    const float inv = 1.0f / den;

    float out[8] = {};
    #pragma unroll
    for (int j = 0; j < 7; ++j) {
        const int tj = tbase + (j << sh);
        float vf[8];
        unpack8(*reinterpret_cast<const uint4*>(Vl + cbase + (size_t)tj * 1024), vf);
        #pragma unroll
        for (int i = 0; i < 8; ++i) out[i] = fmaf(sc[j], vf[i], out[i]);
    }

    short8 ov;
    #pragma unroll
    for (int i = 0; i < 8; ++i) ov[i] = (short)f2bf(out[i] * inv);
    *reinterpret_cast<short8*>(const_cast<ushortT*>(O + qoff)) = ov;
}

// ---------------- launcher ----------------
extern "C" void kernel_launch(void* const* d_in, const int* in_sizes, int n_in,
                              void* d_out, int out_size, void* d_ws, size_t ws_size,
                              hipStream_t stream)
{
    const float* x  = (const float*)d_in[0];
    const float* wq = (const float*)d_in[1];
    const float* bq = (const float*)d_in[2];
    const float* wk = (const float*)d_in[3];
    const float* bk = (const float*)d_in[4];
    const float* wv = (const float*)d_in[5];
    const float* bv = (const float*)d_in[6];
    const float* wp = (const float*)d_in[7];
    const float* bp = (const float*)d_in[8];

    const int B = 4, T = 8192, C = 1024;
    const int M = B * T;                    // 32768
    const size_t MC = (size_t)M * C;        // 33,554,432

    char* ws = (char*)d_ws;
    ushortT* xb    = (ushortT*)ws;                                  // 64MB (reused as attn out)
    ushortT* wallb = (ushortT*)(ws + (size_t)64 * 1024 * 1024);     // 8MB: [wq][wk][wv][wp]
    ushortT* wpb   = wallb + (size_t)3 * C * C;
    ushortT* qlin  = (ushortT*)(ws + (size_t)72 * 1024 * 1024);     // 64MB (klin,vlin follow)
    ushortT* klin  = qlin + MC;
    ushortT* vlin  = klin + MC;
    float2*  tab   = (float2*)(ws + (size_t)264 * 1024 * 1024);     // 1MB
    float*   bqkv  = (float*)(ws + (size_t)266 * 1024 * 1024);      // 12KB

    float* y     = (float*)d_out;
    float* presK = y + MC;                  // presV = presK + MC (contiguous)

    rope_table_kernel<<<512, 256, 0, stream>>>(tab);
    pack_bias_kernel<<<12, 256, 0, stream>>>(bq, bk, bv, bqkv);

    f32_to_bf16_kernel<<<(int)(MC / 4 / 256), 256, 0, stream>>>(x, xb, (int)(MC / 4));
    wconv_kernel<<<4 * (C * C / 4) / 256, 256, 0, stream>>>(wq, wk, wv, wp, wallb);

    // merged qkv dispatch: grid 3072 = 3 proj x 1024 blocks (256x128 tiles)
    gemm_wide_kernel<3><<<3072, 512, 0, stream>>>(
        xb, wallb, bqkv, tab, qlin, presK, M, C, C);

    natt_kernel<<<(B * 16 * T) / 32, 256, 0, stream>>>(qlin, klin, vlin, xb);

    // output projection: grid 1024
    gemm_wide_kernel<2><<<1024, 512, 0, stream>>>(
        xb, wpb, bp, tab, nullptr, y, M, C, C);
}